// Round 2
// baseline (262.369 us; speedup 1.0000x reference)
//
#include <hip/hip_runtime.h>
#include <hip/hip_bf16.h>
#include <stdint.h>

// Problem constants (fixed by reference)
#define LQ   2048
#define NH   16
#define DD   128
#define NB   2
#define QBLK 64
#define KBLK 32
#define ROWSTR (NH*DD)   // 2048 floats between consecutive seq rows

typedef float f32x4 __attribute__((ext_vector_type(4)));
typedef short s16x4 __attribute__((ext_vector_type(4)));
typedef short s16x8 __attribute__((ext_vector_type(8)));

__device__ __forceinline__ short f2bf(float f) {
  union { float f; uint32_t u; } v; v.f = f;
  uint32_t r = (v.u + 0x7FFFu + ((v.u >> 16) & 1u)) >> 16;   // RNE
  return (short)(uint16_t)r;
}

__device__ __forceinline__ s16x4 cvt4(f32x4 x) {
  s16x4 r; r[0] = f2bf(x[0]); r[1] = f2bf(x[1]); r[2] = f2bf(x[2]); r[3] = f2bf(x[3]);
  return r;
}

// low 32 bits of a flat shared address == LDS byte offset (gfx9 apertures are
// defined by the top 16 bits; low 32 bits pass through)
__device__ __forceinline__ uint32_t lds_u32(const void* p) {
  return (uint32_t)(uint64_t)p;
}

// hardware transpose read: with addr = base128 + 8*slot, delivers column `slot`
// of the 128B-aligned 4x16 bf16 block: elements addr/2 + {0,16,32,48}  [m156]
__device__ __forceinline__ s16x4 tr16(uint32_t addr) {
  s16x4 d;
  asm volatile("ds_read_b64_tr_b16 %0, %1" : "=v"(d) : "v"(addr) : "memory");
  return d;
}

__global__ __launch_bounds__(256) void qattn_fwd(
    const float* __restrict__ keys, const float* __restrict__ values,
    float* __restrict__ out)
{
  // K tile row-major [32][132] (pad 132 keeps frag reads + writes conflict-free)
  __shared__ short K_lds[KBLK * 132];
  // V tile: 16 subtiles of [16][16] bf16, contiguous (512B stride, 128B-aligned
  // as required by ds_read_b64_tr_b16's block addressing)
  __shared__ short V_lds[16 * 256];

  const int tid  = threadIdx.x;
  const int wid  = tid >> 6;      // 0..3 waves
  const int lane = tid & 63;
  const int l15  = lane & 15;
  const int lhi  = lane >> 4;     // 0..3

  // XCD-bijective swizzle: each XCD owns 4 (b,h) slices (2MB K+V each -> L2)
  const int wg   = blockIdx.x;          // 0..1023
  const int xcd  = wg & 7;
  const int slot = wg >> 3;             // 0..127
  const int bh   = xcd * 4 + (slot >> 5);
  const int qt   = slot & 31;
  const int b    = bh >> 4;
  const int h    = bh & 15;
  const int q0   = qt * QBLK;

  const float* Kg = keys   + ((size_t)b * LQ * ROWSTR) + (size_t)h * DD;
  const float* Vg = values + ((size_t)b * LQ * ROWSTR) + (size_t)h * DD;
  float*       Og = out    + ((size_t)b * LQ * ROWSTR) + (size_t)h * DD;

  // ---- Q fragments (Q := values rows), straight from global, f32 -> bf16 ----
  // B-operand: lane holds Q[q = l15][k = 32c + 16*(e/4) + 4*lhi + e%4]
  const int qg = q0 + wid * 16 + l15;   // this lane's q-row (also softmax q)
  const float* Qrow = Vg + (size_t)qg * ROWSTR;
  s16x8 qf[4];
#pragma unroll
  for (int c = 0; c < 4; ++c) {
    f32x4 lo = *(const f32x4*)(Qrow + 32 * c + 4 * lhi);
    f32x4 hi = *(const f32x4*)(Qrow + 32 * c + 16 + 4 * lhi);
    qf[c] = __builtin_shufflevector(cvt4(lo), cvt4(hi), 0, 1, 2, 3, 4, 5, 6, 7);
  }

  // O accumulator: o[df][r] = O[q = 4*lhi + r][d = df*16 + l15]
  f32x4 o[8];
#pragma unroll
  for (int i = 0; i < 8; ++i) o[i] = f32x4{0.f, 0.f, 0.f, 0.f};
  float m  = -1e30f;   // running max (exp2-logit units), keyed by q = l15
  float ll = 0.0f;     // running denom

  // logits * (0.5/sqrt(128)) * log2(e)  (quantum_score cancels in softmax)
  const float CS = 0.5f * 0.08838834764831845f * 1.4426950408889634f;
  const int q_wave_hi = q0 + wid * 16 + 15;
  const int ntiles = q0 / KBLK + 2;

  for (int t = 0; t < ntiles; ++t) {
    const int s0 = t * KBLK;
    if (t > 0) __syncthreads();   // previous tile's readers done

    // ---- stage K (f32 global -> bf16 LDS), row-major padded ----
#pragma unroll
    for (int p = 0; p < 4; ++p) {
      const int r  = (tid >> 5) + 8 * p;   // 0..31
      const int c4 = tid & 31;             // float4 column
      f32x4 kk = *(const f32x4*)(Kg + (size_t)(s0 + r) * ROWSTR + 4 * c4);
      *(s16x4*)&K_lds[r * 132 + 4 * c4] = cvt4(kk);
    }
    // ---- stage V into [sub][16][16] subtiles; lane->row/col remap spreads
    //      write banks: bank = 8*(g&3) + 2*((g>>2)&3) -> all 32, floor ----
#pragma unroll
    for (int p = 0; p < 4; ++p) {
      const int g  = tid + 256 * p;
      const int r  = (g & 3) | ((g >> 7) << 2);   // 0..31
      const int c4 = (g >> 2) & 31;
      f32x4 vv = *(const f32x4*)(Vg + (size_t)(s0 + r) * ROWSTR + 4 * c4);
      const int sub = (r >> 4) * 8 + (c4 >> 2);   // s_hi*8 + d_blk
      *(s16x4*)&V_lds[sub * 256 + (r & 15) * 16 + 4 * (c4 & 3)] = cvt4(vv);
    }
    __syncthreads();

    if (s0 > q_wave_hi) continue;   // tile fully masked for this wave

    // ---- QK^T swapped: sT = K_blk · Q^T  -> S^T[s][q] ----
    f32x4 sT0 = f32x4{0.f, 0.f, 0.f, 0.f};
    f32x4 sT1 = f32x4{0.f, 0.f, 0.f, 0.f};
#pragma unroll
    for (int c = 0; c < 4; ++c) {
      s16x4 a0 = *(const s16x4*)&K_lds[l15 * 132 + 32 * c + 4 * lhi];
      s16x4 b0 = *(const s16x4*)&K_lds[l15 * 132 + 32 * c + 16 + 4 * lhi];
      s16x4 a1 = *(const s16x4*)&K_lds[(16 + l15) * 132 + 32 * c + 4 * lhi];
      s16x4 b1 = *(const s16x4*)&K_lds[(16 + l15) * 132 + 32 * c + 16 + 4 * lhi];
      s16x8 kf0 = __builtin_shufflevector(a0, b0, 0, 1, 2, 3, 4, 5, 6, 7);
      s16x8 kf1 = __builtin_shufflevector(a1, b1, 0, 1, 2, 3, 4, 5, 6, 7);
      sT0 = __builtin_amdgcn_mfma_f32_16x16x32_bf16(kf0, qf[c], sT0, 0, 0, 0);
      sT1 = __builtin_amdgcn_mfma_f32_16x16x32_bf16(kf1, qf[c], sT1, 0, 0, 0);
    }

    // ---- online softmax: lane owns 8 scores for q = l15, s = s0+blk*16+4*lhi+r
    float z[8];
#pragma unroll
    for (int i = 0; i < 4; ++i) { z[i] = sT0[i] * CS; z[4 + i] = sT1[i] * CS; }
    if (s0 + KBLK - 1 > qg) {   // causal mask (strict upper triangle)
#pragma unroll
      for (int blk = 0; blk < 2; ++blk)
#pragma unroll
        for (int r = 0; r < 4; ++r)
          if (s0 + blk * 16 + 4 * lhi + r > qg) z[blk * 4 + r] = -1e30f;
    }
    float tm = z[0];
#pragma unroll
    for (int i = 1; i < 8; ++i) tm = fmaxf(tm, z[i]);
    tm = fmaxf(tm, __shfl_xor(tm, 16));
    tm = fmaxf(tm, __shfl_xor(tm, 32));
    const float mn = fmaxf(m, tm);
    const float alpha = exp2f(m - mn);
    m = mn;
    float rs = 0.f;
    s16x8 pf;
#pragma unroll
    for (int i = 0; i < 8; ++i) {
      float p = exp2f(z[i] - mn);
      rs += p;
      pf[i] = f2bf(p);
    }
    rs += __shfl_xor(rs, 16);
    rs += __shfl_xor(rs, 32);
    ll = ll * alpha + rs;

    // ---- rescale O (alpha keyed by q=l15 -> broadcast to q=4*lhi+r owners) ----
    float ar[4];
#pragma unroll
    for (int r = 0; r < 4; ++r) ar[r] = __shfl(alpha, 4 * lhi + r);
#pragma unroll
    for (int df = 0; df < 8; ++df)
#pragma unroll
      for (int r = 0; r < 4; ++r) o[df][r] *= ar[r];

    // ---- PV: O += P · V ; V fragments via hardware transpose read ----
    // standard m156 pattern: addr = subtile_base + 8*lane; lane gets
    // subtile element (row = 4*lhi + j, col = l15) = V[s_local][d]
    const uint32_t vbase = lds_u32(&V_lds[0]) + 8u * (uint32_t)lane;
    s16x4 vlo[8], vhi[8];
#pragma unroll
    for (int df = 0; df < 8; ++df) {
      vlo[df] = tr16(vbase + 512u * (uint32_t)df);         // s_hi = 0
      vhi[df] = tr16(vbase + 512u * (uint32_t)(8 + df));   // s_hi = 1
    }
    asm volatile("s_waitcnt lgkmcnt(0)" ::: "memory");
    __builtin_amdgcn_sched_barrier(0);
#pragma unroll
    for (int df = 0; df < 8; ++df) {
      s16x8 vf = __builtin_shufflevector(vlo[df], vhi[df], 0, 1, 2, 3, 4, 5, 6, 7);
      o[df] = __builtin_amdgcn_mfma_f32_16x16x32_bf16(pf, vf, o[df], 0, 0, 0);
    }
  }

  // ---- epilogue: O /= l, store f32 ----
  const float linv = 1.0f / ll;
#pragma unroll
  for (int r = 0; r < 4; ++r) {
    const float lr = __shfl(linv, 4 * lhi + r);
    float* orow = Og + (size_t)(q0 + wid * 16 + 4 * lhi + r) * ROWSTR;
#pragma unroll
    for (int df = 0; df < 8; ++df)
      orow[df * 16 + l15] = o[df][r] * lr;
  }
}

extern "C" void kernel_launch(void* const* d_in, const int* in_sizes, int n_in,
                              void* d_out, int out_size, void* d_ws, size_t ws_size,
                              hipStream_t stream) {
  // inputs: 0=queries (dead), 1=keys, 2=values, 3=q_params (dead: softmax-shift cancels)
  const float* keys   = (const float*)d_in[1];
  const float* values = (const float*)d_in[2];
  float*       out    = (float*)d_out;
  dim3 grid(NB * NH * (LQ / QBLK));   // 1024, %8==0 -> bijective XCD swizzle
  dim3 block(256);
  hipLaunchKernelGGL(qattn_fwd, grid, block, 0, stream, keys, values, out);
}

// Round 3
// 112.510 us; speedup vs baseline: 2.3320x; 2.3320x over previous
//
#include <hip/hip_runtime.h>
#include <hip/hip_bf16.h>
#include <stdint.h>

// Problem constants (fixed by reference)
#define LQ   2048
#define NH   16
#define DD   128
#define NB   2
#define QBLK 128          // rows per block strip (8 waves x 16)
#define KBLK 32           // K/V tile rows
#define NQT  (LQ/QBLK)    // 16 strips; paired qt <-> 15-qt for balance
#define ROWSTR (NH*DD)    // 2048 floats between consecutive seq rows

typedef float f32x4 __attribute__((ext_vector_type(4)));
typedef short s16x4 __attribute__((ext_vector_type(4)));
typedef short s16x8 __attribute__((ext_vector_type(8)));

__device__ __forceinline__ short f2bf(float f) {
  union { float f; uint32_t u; } v; v.f = f;
  uint32_t r = (v.u + 0x7FFFu + ((v.u >> 16) & 1u)) >> 16;   // RNE
  return (short)(uint16_t)r;
}

__device__ __forceinline__ s16x4 cvt4(f32x4 x) {
  s16x4 r; r[0] = f2bf(x[0]); r[1] = f2bf(x[1]); r[2] = f2bf(x[2]); r[3] = f2bf(x[3]);
  return r;
}

__device__ __forceinline__ uint32_t lds_u32(const void* p) {
  return (uint32_t)(uint64_t)p;
}

// hardware transpose read (verified config): addr = subtile_base + 8*lane over a
// contiguous 128B-aligned [16][16] bf16 subtile -> lane gets col l15, rows 4*lhi+j
__device__ __forceinline__ s16x4 tr16(uint32_t addr) {
  s16x4 d;
  asm volatile("ds_read_b64_tr_b16 %0, %1" : "=v"(d) : "v"(addr) : "memory");
  return d;
}

struct Stage { f32x4 k0, k1, v0, v1; };

__device__ __forceinline__ Stage load_tile(const float* __restrict__ Kg,
                                           const float* __restrict__ Vg,
                                           int s0, int tid) {
  Stage st;
  const int rk = tid >> 5;          // 0..15
  const int c4 = tid & 31;
  st.k0 = *(const f32x4*)(Kg + (size_t)(s0 + rk) * ROWSTR + 4 * c4);
  st.k1 = *(const f32x4*)(Kg + (size_t)(s0 + rk + 16) * ROWSTR + 4 * c4);
  const int g0 = tid;
  const int rv0 = (g0 & 3) | ((g0 >> 7) << 2), cv0 = (g0 >> 2) & 31;
  st.v0 = *(const f32x4*)(Vg + (size_t)(s0 + rv0) * ROWSTR + 4 * cv0);
  const int g1 = tid + 512;
  const int rv1 = (g1 & 3) | ((g1 >> 7) << 2), cv1 = (g1 >> 2) & 31;
  st.v1 = *(const f32x4*)(Vg + (size_t)(s0 + rv1) * ROWSTR + 4 * cv1);
  return st;
}

__device__ __forceinline__ void write_tile(short* Kb, short* Vb,
                                           const Stage& st, int tid) {
  const int rk = tid >> 5;
  const int c4 = tid & 31;
  *(s16x4*)&Kb[rk * 132 + 4 * c4]        = cvt4(st.k0);
  *(s16x4*)&Kb[(rk + 16) * 132 + 4 * c4] = cvt4(st.k1);
  const int g0 = tid;
  const int rv0 = (g0 & 3) | ((g0 >> 7) << 2), cv0 = (g0 >> 2) & 31;
  const int sub0 = (rv0 >> 4) * 8 + (cv0 >> 2);
  *(s16x4*)&Vb[sub0 * 256 + (rv0 & 15) * 16 + 4 * (cv0 & 3)] = cvt4(st.v0);
  const int g1 = tid + 512;
  const int rv1 = (g1 & 3) | ((g1 >> 7) << 2), cv1 = (g1 >> 2) & 31;
  const int sub1 = (rv1 >> 4) * 8 + (cv1 >> 2);
  *(s16x4*)&Vb[sub1 * 256 + (rv1 & 15) * 16 + 4 * (cv1 & 3)] = cvt4(st.v1);
}

__global__ __launch_bounds__(512, 2) void qattn_fwd(
    const float* __restrict__ keys, const float* __restrict__ values,
    float* __restrict__ out)
{
  // double-buffered tiles; layouts identical to the verified round-2 kernel
  __shared__ short K_lds[2][KBLK * 132];   // row-major padded 132
  __shared__ short V_lds[2][16 * 256];     // 16x [16][16] subtiles, 512B stride

  const int tid  = threadIdx.x;
  const int wid  = tid >> 6;      // 0..7 waves
  const int lane = tid & 63;
  const int l15  = lane & 15;
  const int lhi  = lane >> 4;     // 0..3

  // grid = 256: wg = pair*32 + bh  (same-bh blocks share an XCD's L2)
  const int wg   = blockIdx.x;
  const int bh   = wg & 31;
  const int pair = wg >> 5;             // 0..7
  const int b    = bh >> 4;
  const int h    = bh & 15;

  const float* Kg = keys   + ((size_t)b * LQ * ROWSTR) + (size_t)h * DD;
  const float* Vg = values + ((size_t)b * LQ * ROWSTR) + (size_t)h * DD;
  float*       Og = out    + ((size_t)b * LQ * ROWSTR) + (size_t)h * DD;

  // logits * (0.5/sqrt(128)) * log2(e); quantum_score cancels in softmax
  const float CS = 0.5f * 0.08838834764831845f * 1.4426950408889634f;

  // two perfectly-balancing strips: qt and 15-qt  (total tiles = 68 for all blocks)
  for (int sp = 0; sp < 2; ++sp) {
    const int qt = sp ? (NQT - 1 - pair) : pair;
    const int q0 = qt * QBLK;
    const int nt = 4 * qt + 4;              // tiles covering s <= q0+127

    // ---- Q fragments (Q := values rows), global f32 -> bf16 regs ----
    const int qg = q0 + wid * 16 + l15;     // this lane's q-row
    const float* Qrow = Vg + (size_t)qg * ROWSTR;
    s16x8 qf[4];
#pragma unroll
    for (int c = 0; c < 4; ++c) {
      f32x4 lo = *(const f32x4*)(Qrow + 32 * c + 4 * lhi);
      f32x4 hi = *(const f32x4*)(Qrow + 32 * c + 16 + 4 * lhi);
      qf[c] = __builtin_shufflevector(cvt4(lo), cvt4(hi), 0, 1, 2, 3, 4, 5, 6, 7);
    }

    f32x4 o[8];
#pragma unroll
    for (int i = 0; i < 8; ++i) o[i] = f32x4{0.f, 0.f, 0.f, 0.f};
    float m  = -1e30f;
    float ll = 0.0f;
    const int q_wave_hi = q0 + wid * 16 + 15;

    // ---- prologue: stage tile 0 into buf 0 ----
    {
      Stage st = load_tile(Kg, Vg, 0, tid);
      __syncthreads();                       // strip B: prior strip fully done
      write_tile(K_lds[0], V_lds[0], st, tid);
    }
    __syncthreads();

    for (int t = 0; t < nt; ++t) {
      const int cur = t & 1;
      const int s0  = t * KBLK;

      // issue next tile's global loads early (latency hides under compute)
      Stage st;
      const bool more = (t + 1) < nt;
      if (more) st = load_tile(Kg, Vg, (t + 1) * KBLK, tid);

      if (s0 <= q_wave_hi) {                 // per-wave causal skip (compute only)
        const short* Kb = K_lds[cur];
        short*       Vb = V_lds[cur];

        // ---- QK^T swapped: sT = K_blk · Q^T -> S^T[s][q] ----
        f32x4 sT0 = f32x4{0.f, 0.f, 0.f, 0.f};
        f32x4 sT1 = f32x4{0.f, 0.f, 0.f, 0.f};
#pragma unroll
        for (int c = 0; c < 4; ++c) {
          s16x4 a0 = *(const s16x4*)&Kb[l15 * 132 + 32 * c + 4 * lhi];
          s16x4 b0 = *(const s16x4*)&Kb[l15 * 132 + 32 * c + 16 + 4 * lhi];
          s16x4 a1 = *(const s16x4*)&Kb[(16 + l15) * 132 + 32 * c + 4 * lhi];
          s16x4 b1 = *(const s16x4*)&Kb[(16 + l15) * 132 + 32 * c + 16 + 4 * lhi];
          s16x8 kf0 = __builtin_shufflevector(a0, b0, 0, 1, 2, 3, 4, 5, 6, 7);
          s16x8 kf1 = __builtin_shufflevector(a1, b1, 0, 1, 2, 3, 4, 5, 6, 7);
          sT0 = __builtin_amdgcn_mfma_f32_16x16x32_bf16(kf0, qf[c], sT0, 0, 0, 0);
          sT1 = __builtin_amdgcn_mfma_f32_16x16x32_bf16(kf1, qf[c], sT1, 0, 0, 0);
        }

        // ---- online softmax: lane owns q = l15, s = s0 + blk*16 + 4*lhi + r ----
        float z[8];
#pragma unroll
        for (int i = 0; i < 4; ++i) { z[i] = sT0[i] * CS; z[4 + i] = sT1[i] * CS; }
        if (s0 + KBLK - 1 > qg) {
#pragma unroll
          for (int blk = 0; blk < 2; ++blk)
#pragma unroll
            for (int r = 0; r < 4; ++r)
              if (s0 + blk * 16 + 4 * lhi + r > qg) z[blk * 4 + r] = -1e30f;
        }
        float tm = z[0];
#pragma unroll
        for (int i = 1; i < 8; ++i) tm = fmaxf(tm, z[i]);
        tm = fmaxf(tm, __shfl_xor(tm, 16));
        tm = fmaxf(tm, __shfl_xor(tm, 32));
        const float mn = fmaxf(m, tm);
        const float alpha = exp2f(m - mn);
        m = mn;
        float rs = 0.f;
        s16x8 pf;
#pragma unroll
        for (int i = 0; i < 8; ++i) {
          float p = exp2f(z[i] - mn);
          rs += p;
          pf[i] = f2bf(p);
        }
        rs += __shfl_xor(rs, 16);
        rs += __shfl_xor(rs, 32);
        ll = ll * alpha + rs;

        float ar[4];
#pragma unroll
        for (int r = 0; r < 4; ++r) ar[r] = __shfl(alpha, 4 * lhi + r);
#pragma unroll
        for (int df = 0; df < 8; ++df)
#pragma unroll
          for (int r = 0; r < 4; ++r) o[df][r] *= ar[r];

        // ---- PV via hardware transpose reads (verified pattern) ----
        const uint32_t vbase = lds_u32(&Vb[0]) + 8u * (uint32_t)lane;
        s16x4 vlo[8], vhi[8];
#pragma unroll
        for (int df = 0; df < 8; ++df) {
          vlo[df] = tr16(vbase + 512u * (uint32_t)df);         // s_lo 16 rows
          vhi[df] = tr16(vbase + 512u * (uint32_t)(8 + df));   // s_hi 16 rows
        }
        asm volatile("s_waitcnt lgkmcnt(0)" ::: "memory");
        __builtin_amdgcn_sched_barrier(0);
#pragma unroll
        for (int df = 0; df < 8; ++df) {
          s16x8 vf = __builtin_shufflevector(vlo[df], vhi[df], 0, 1, 2, 3, 4, 5, 6, 7);
          o[df] = __builtin_amdgcn_mfma_f32_16x16x32_bf16(pf, vf, o[df], 0, 0, 0);
        }
      }

      // write next tile into the other buffer (vmcnt wait inserted by compiler)
      if (more) write_tile(K_lds[cur ^ 1], V_lds[cur ^ 1], st, tid);
      __syncthreads();                       // single barrier per tile
    }

    // ---- epilogue: O /= l, store f32 ----
    const float linv = 1.0f / ll;
#pragma unroll
    for (int r = 0; r < 4; ++r) {
      const float lr = __shfl(linv, 4 * lhi + r);
      float* orow = Og + (size_t)(q0 + wid * 16 + 4 * lhi + r) * ROWSTR;
#pragma unroll
      for (int df = 0; df < 8; ++df)
        orow[df * 16 + l15] = o[df][r] * lr;
    }
  }
}

extern "C" void kernel_launch(void* const* d_in, const int* in_sizes, int n_in,
                              void* d_out, int out_size, void* d_ws, size_t ws_size,
                              hipStream_t stream) {
  // inputs: 0=queries (dead), 1=keys, 2=values, 3=q_params (dead: softmax shift)
  const float* keys   = (const float*)d_in[1];
  const float* values = (const float*)d_in[2];
  float*       out    = (float*)d_out;
  dim3 grid(NB * NH * (NQT / 2));   // 256 blocks: one per CU, perfectly balanced
  dim3 block(512);
  hipLaunchKernelGGL(qattn_fwd, grid, block, 0, stream, keys, values, out);
}

// Round 4
// 86.302 us; speedup vs baseline: 3.0401x; 1.3037x over previous
//
#include <hip/hip_runtime.h>
#include <hip/hip_bf16.h>
#include <stdint.h>

// Problem constants (fixed by reference)
#define LQ   2048
#define NH   16
#define DD   128
#define NB   2
#define QBLK 128          // rows per block strip (8 waves x 16)
#define KBLK 64           // K/V tile rows
#define NQT  (LQ/QBLK)    // 16 strips; paired qt <-> 15-qt for balance
#define ROWSTR (NH*DD)    // 2048 floats between consecutive seq rows

typedef float f32x4 __attribute__((ext_vector_type(4)));
typedef short s16x4 __attribute__((ext_vector_type(4)));
typedef short s16x8 __attribute__((ext_vector_type(8)));

// scalar cast -> compiler packs into v_cvt_pk_bf16_f32 (m240: beats hand asm)
__device__ __forceinline__ short f2bf(float f) {
  union { __hip_bfloat16 h; short s; } u;
  u.h = __float2bfloat16(f);
  return u.s;
}

__device__ __forceinline__ s16x4 cvt4(f32x4 x) {
  s16x4 r; r[0] = f2bf(x[0]); r[1] = f2bf(x[1]); r[2] = f2bf(x[2]); r[3] = f2bf(x[3]);
  return r;
}

__device__ __forceinline__ uint32_t lds_u32(const void* p) {
  return (uint32_t)(uint64_t)p;
}

// hardware transpose read (verified config): addr = subtile_base + 8*lane over a
// contiguous 128B-aligned [16][16] bf16 subtile -> lane gets col l15, rows 4*lhi+j
__device__ __forceinline__ s16x4 tr16(uint32_t addr) {
  s16x4 d;
  asm volatile("ds_read_b64_tr_b16 %0, %1" : "=v"(d) : "v"(addr) : "memory");
  return d;
}

struct Stage { f32x4 k[4]; f32x4 v[4]; };

__device__ __forceinline__ Stage load_tile(const float* __restrict__ Kg,
                                           const float* __restrict__ Vg,
                                           int s0, int tid) {
  Stage st;
  const int rk = tid >> 5;          // 0..15
  const int c4 = tid & 31;
#pragma unroll
  for (int j = 0; j < 4; ++j)
    st.k[j] = *(const f32x4*)(Kg + (size_t)(s0 + rk + 16 * j) * ROWSTR + 4 * c4);
#pragma unroll
  for (int p = 0; p < 4; ++p) {
    const int g = tid + 512 * p;
    const int rv = (g & 3) | ((g >> 7) << 2);   // 0..63, bijective
    const int cv = (g >> 2) & 31;
    st.v[p] = *(const f32x4*)(Vg + (size_t)(s0 + rv) * ROWSTR + 4 * cv);
  }
  return st;
}

__device__ __forceinline__ void write_tile(short* Kb, short* Vb,
                                           const Stage& st, int tid) {
  const int rk = tid >> 5;
  const int c4 = tid & 31;
#pragma unroll
  for (int j = 0; j < 4; ++j)
    *(s16x4*)&Kb[(rk + 16 * j) * 132 + 4 * c4] = cvt4(st.k[j]);
#pragma unroll
  for (int p = 0; p < 4; ++p) {
    const int g = tid + 512 * p;
    const int rv = (g & 3) | ((g >> 7) << 2);
    const int cv = (g >> 2) & 31;
    const int sub = (rv >> 4) * 8 + (cv >> 2);   // s_hi*8 + d_blk, 0..31
    *(s16x4*)&Vb[sub * 256 + (rv & 15) * 16 + 4 * (cv & 3)] = cvt4(st.v[p]);
  }
}

__global__ __launch_bounds__(512, 2) void qattn_fwd(
    const float* __restrict__ keys, const float* __restrict__ values,
    float* __restrict__ out)
{
  __shared__ short K_lds[2][KBLK * 132];   // row-major padded 132 (16.5 KB ea)
  __shared__ short V_lds[2][32 * 256];     // 32x [16][16] subtiles (16 KB ea)

  const int tid  = threadIdx.x;
  const int wid  = tid >> 6;      // 0..7 waves
  const int lane = tid & 63;
  const int l15  = lane & 15;
  const int lhi  = lane >> 4;     // 0..3

  // grid = 256: wg = pair*32 + bh  (same-bh blocks share an XCD's L2)
  const int wg   = blockIdx.x;
  const int bh   = wg & 31;
  const int pair = wg >> 5;             // 0..7
  const int b    = bh >> 4;
  const int h    = bh & 15;

  const float* Kg = keys   + ((size_t)b * LQ * ROWSTR) + (size_t)h * DD;
  const float* Vg = values + ((size_t)b * LQ * ROWSTR) + (size_t)h * DD;
  float*       Og = out    + ((size_t)b * LQ * ROWSTR) + (size_t)h * DD;

  // logits * (0.5/sqrt(128)) * log2(e); folded into Q fragments below.
  // quantum_score cancels in softmax (uniform shift).
  const float CS = 0.5f * 0.08838834764831845f * 1.4426950408889634f;

  // two perfectly-balancing strips: qt and 15-qt (34 staged tiles per block)
  for (int sp = 0; sp < 2; ++sp) {
    const int qt = sp ? (NQT - 1 - pair) : pair;
    const int q0 = qt * QBLK;
    const int nt = 2 * qt + 2;              // 64-row tiles covering s <= q0+127

    // ---- Q fragments (Q := values rows), CS pre-folded, f32 -> bf16 regs ----
    const int qg = q0 + wid * 16 + l15;     // this lane's q-row
    const float* Qrow = Vg + (size_t)qg * ROWSTR;
    s16x8 qf[4];
#pragma unroll
    for (int c = 0; c < 4; ++c) {
      f32x4 lo = *(const f32x4*)(Qrow + 32 * c + 4 * lhi);
      f32x4 hi = *(const f32x4*)(Qrow + 32 * c + 16 + 4 * lhi);
      lo *= CS; hi *= CS;
      qf[c] = __builtin_shufflevector(cvt4(lo), cvt4(hi), 0, 1, 2, 3, 4, 5, 6, 7);
    }

    f32x4 o[8];
#pragma unroll
    for (int i = 0; i < 8; ++i) o[i] = f32x4{0.f, 0.f, 0.f, 0.f};
    float m  = -1e30f;   // running max (exp2-logit units), keyed by q = l15
    float ll = 0.0f;
    const int q_wave_hi = q0 + wid * 16 + 15;

    // ---- prologue: stage tile 0 into buf 0 ----
    {
      Stage st = load_tile(Kg, Vg, 0, tid);
      __syncthreads();                       // strip B: prior strip fully done
      write_tile(K_lds[0], V_lds[0], st, tid);
    }
    __syncthreads();

    for (int t = 0; t < nt; ++t) {
      const int cur = t & 1;
      const int s0  = t * KBLK;

      // issue next tile's global loads early (latency hides under compute)
      Stage st;
      const bool more = (t + 1) < nt;
      if (more) st = load_tile(Kg, Vg, (t + 1) * KBLK, tid);

      if (s0 <= q_wave_hi) {                 // per-wave causal skip
        const short* Kb = K_lds[cur];
        short*       Vb = V_lds[cur];

        // ---- QK^T swapped: sT[sb] = K_sb · Q^T -> S^T[s][q] ----
        f32x4 sT[4];
#pragma unroll
        for (int sb = 0; sb < 4; ++sb) sT[sb] = f32x4{0.f, 0.f, 0.f, 0.f};
        __builtin_amdgcn_s_setprio(1);
#pragma unroll
        for (int c = 0; c < 4; ++c) {
#pragma unroll
          for (int sb = 0; sb < 4; ++sb) {
            s16x4 a = *(const s16x4*)&Kb[(sb * 16 + l15) * 132 + 32 * c + 4 * lhi];
            s16x4 bb = *(const s16x4*)&Kb[(sb * 16 + l15) * 132 + 32 * c + 16 + 4 * lhi];
            s16x8 kf = __builtin_shufflevector(a, bb, 0, 1, 2, 3, 4, 5, 6, 7);
            sT[sb] = __builtin_amdgcn_mfma_f32_16x16x32_bf16(kf, qf[c], sT[sb], 0, 0, 0);
          }
        }
        __builtin_amdgcn_s_setprio(0);

        // ---- online softmax: lane owns q=l15, s = s0 + sb*16 + 4*lhi + r ----
        float z[16];
#pragma unroll
        for (int sb = 0; sb < 4; ++sb)
#pragma unroll
          for (int r = 0; r < 4; ++r) z[sb * 4 + r] = sT[sb][r];
        if (s0 + KBLK - 1 > qg) {            // diagonal tile: causal mask
#pragma unroll
          for (int sb = 0; sb < 4; ++sb)
#pragma unroll
            for (int r = 0; r < 4; ++r)
              if (s0 + sb * 16 + 4 * lhi + r > qg) z[sb * 4 + r] = -1e30f;
        }
        float tm = z[0];
#pragma unroll
        for (int i = 1; i < 16; ++i) tm = fmaxf(tm, z[i]);
        tm = fmaxf(tm, __shfl_xor(tm, 16));
        tm = fmaxf(tm, __shfl_xor(tm, 32));

        // defer-max (T13): only rescale when max grew past THR=8 (exp2 units)
        if (!__all(tm - m <= 8.0f)) {
          const float mn = fmaxf(m, tm);
          const float alpha = exp2f(m - mn);
          m = mn;
          float ar[4];
#pragma unroll
          for (int r = 0; r < 4; ++r) ar[r] = __shfl(alpha, 4 * lhi + r);
#pragma unroll
          for (int df = 0; df < 8; ++df)
#pragma unroll
            for (int r = 0; r < 4; ++r) o[df][r] *= ar[r];
          ll *= alpha;
        }
        float rs = 0.f;
        s16x8 pf0, pf1;
#pragma unroll
        for (int i = 0; i < 8; ++i) {
          float p = exp2f(z[i] - m);
          rs += p;
          pf0[i] = f2bf(p);
        }
#pragma unroll
        for (int i = 0; i < 8; ++i) {
          float p = exp2f(z[8 + i] - m);
          rs += p;
          pf1[i] = f2bf(p);
        }
        rs += __shfl_xor(rs, 16);
        rs += __shfl_xor(rs, 32);
        ll += rs;

        // ---- PV via hardware transpose reads, two 32-row k-slots ----
        const uint32_t vbase = lds_u32(&Vb[0]) + 8u * (uint32_t)lane;
#pragma unroll
        for (int ks = 0; ks < 2; ++ks) {
          s16x4 vlo[8], vhi[8];
#pragma unroll
          for (int df = 0; df < 8; ++df) {
            vlo[df] = tr16(vbase + 512u * (uint32_t)(16 * ks + df));
            vhi[df] = tr16(vbase + 512u * (uint32_t)(16 * ks + 8 + df));
          }
          asm volatile("s_waitcnt lgkmcnt(0)" ::: "memory");
          __builtin_amdgcn_sched_barrier(0);
          const s16x8 pf = ks ? pf1 : pf0;
          __builtin_amdgcn_s_setprio(1);
#pragma unroll
          for (int df = 0; df < 8; ++df) {
            s16x8 vf = __builtin_shufflevector(vlo[df], vhi[df], 0, 1, 2, 3, 4, 5, 6, 7);
            o[df] = __builtin_amdgcn_mfma_f32_16x16x32_bf16(pf, vf, o[df], 0, 0, 0);
          }
          __builtin_amdgcn_s_setprio(0);
        }
      }

      // write next tile into the other buffer (compiler inserts vmcnt wait)
      if (more) write_tile(K_lds[cur ^ 1], V_lds[cur ^ 1], st, tid);
      __syncthreads();                       // single barrier per tile
    }

    // ---- epilogue: O /= l, store f32 ----
    const float linv = 1.0f / ll;
#pragma unroll
    for (int r = 0; r < 4; ++r) {
      const float lr = __shfl(linv, 4 * lhi + r);
      float* orow = Og + (size_t)(q0 + wid * 16 + 4 * lhi + r) * ROWSTR;
#pragma unroll
      for (int df = 0; df < 8; ++df)
        orow[df * 16 + l15] = o[df][r] * lr;
    }
  }
}

extern "C" void kernel_launch(void* const* d_in, const int* in_sizes, int n_in,
                              void* d_out, int out_size, void* d_ws, size_t ws_size,
                              hipStream_t stream) {
  // inputs: 0=queries (dead), 1=keys, 2=values, 3=q_params (dead: softmax shift)
  const float* keys   = (const float*)d_in[1];
  const float* values = (const float*)d_in[2];
  float*       out    = (float*)d_out;
  dim3 grid(NB * NH * (NQT / 2));   // 256 blocks: one per CU, perfectly balanced
  dim3 block(512);
  hipLaunchKernelGGL(qattn_fwd, grid, block, 0, stream, keys, values, out);
}